// Round 3
// baseline (3082.265 us; speedup 1.0000x reference)
//
#include <hip/hip_runtime.h>
#include <stdint.h>

#define DD 256
#define DINF 128

typedef __attribute__((ext_vector_type(8))) short short8;
typedef __attribute__((ext_vector_type(4))) float f32x4;

__device__ __forceinline__ short f2bf(float f) {
    union { float f; uint32_t u; } c{f};
    uint32_t r = (c.u + 0x7fffu + ((c.u >> 16) & 1u)) >> 16;
    return (short)(uint16_t)r;
}

__device__ __forceinline__ float bf2f(uint16_t b) {
    union { uint32_t u; float f; } c;
    c.u = ((uint32_t)b) << 16;
    return c.f;
}

// ---------------- CSR build ----------------
__global__ void k_hist(const int* __restrict__ rows, int* __restrict__ counts, int E) {
    int e = blockIdx.x * blockDim.x + threadIdx.x;
    if (e < E) atomicAdd(&counts[rows[e] + 1], 1);
}

__global__ void k_scan(const int* __restrict__ counts, int* __restrict__ row_ptr,
                       int* __restrict__ cursor, int n1) {
    __shared__ int tmp[1024];
    __shared__ int carry_s;
    int t = threadIdx.x;
    if (t == 0) carry_s = 0;
    __syncthreads();
    for (int base = 0; base < n1; base += 1024) {
        int i = base + t;
        int v = (i < n1) ? counts[i] : 0;
        tmp[t] = v;
        __syncthreads();
        for (int off = 1; off < 1024; off <<= 1) {
            int a = (t >= off) ? tmp[t - off] : 0;
            __syncthreads();
            tmp[t] += a;
            __syncthreads();
        }
        int incl = tmp[t] + carry_s;
        if (i < n1) { row_ptr[i] = incl; cursor[i] = incl; }
        __syncthreads();
        if (t == 1023) carry_s = incl;
        __syncthreads();
    }
}

__global__ void k_scatter(const int* __restrict__ rows, const int* __restrict__ cols,
                          const float* __restrict__ vals, int* __restrict__ cursor,
                          int* __restrict__ cols_s, float* __restrict__ vals_s, int E) {
    int e = blockIdx.x * blockDim.x + threadIdx.x;
    if (e < E) {
        int r = rows[e];
        int pos = atomicAdd(&cursor[r], 1);
        cols_s[pos] = cols[e];
        vals_s[pos] = vals[e];
    }
}

// ---------------- M = (W*clip(d))@W^T - I  (symmetric; bf16) ----------------
__global__ void k_build_m(const float* __restrict__ W, const float* __restrict__ dvec,
                          uint16_t* __restrict__ Mbf) {
    __shared__ float u[DD];
    int n = blockIdx.x, k = threadIdx.x;
    float dj = dvec[k];
    dj = fminf(fmaxf(dj, 0.f), 1.f);
    u[k] = W[n * DD + k] * dj;
    __syncthreads();
    float acc = 0.f;
    for (int j = 0; j < DD; j++) acc += u[j] * W[k * DD + j];
    acc -= (n == k) ? 1.f : 0.f;
    Mbf[n * DD + k] = (uint16_t)f2bf(acc);
}

// ---------------- init: zn = [x, 0], alpha = alpha0 ----------------
__global__ void k_init(const float* __restrict__ x, const float* __restrict__ alpha0,
                       float* __restrict__ zn, float* __restrict__ alpha, int N) {
    int idx = blockIdx.x * blockDim.x + threadIdx.x;
    int total = N * 64;
    if (idx < total) {
        int row = idx >> 6, c4 = idx & 63;
        float4 v;
        if (c4 < 32) v = ((const float4*)x)[row * 32 + c4];
        else v = make_float4(0.f, 0.f, 0.f, 0.f);
        ((float4*)zn)[idx] = v;
    }
    if (idx < N) alpha[idx] = alpha0[idx];
}

// ---------------- SpMM (fp32 source): az_bf16 = A * z ----------------
__global__ void k_spmm_f32(const float* __restrict__ z, const int* __restrict__ row_ptr,
                           const int* __restrict__ cols_s, const float* __restrict__ vals_s,
                           uint16_t* __restrict__ az, int N) {
    int wave = (int)((blockIdx.x * (size_t)blockDim.x + threadIdx.x) >> 6);
    int lane = threadIdx.x & 63;
    if (wave >= N) return;
    int s = row_ptr[wave], e = row_ptr[wave + 1];
    float4 acc = make_float4(0.f, 0.f, 0.f, 0.f);
    for (int i = s; i < e; i++) {
        int c = cols_s[i];
        float v = vals_s[i];
        float4 zr = ((const float4*)z)[c * 64 + lane];
        acc.x += v * zr.x; acc.y += v * zr.y; acc.z += v * zr.z; acc.w += v * zr.w;
    }
    ushort4 o;
    o.x = (uint16_t)f2bf(acc.x); o.y = (uint16_t)f2bf(acc.y);
    o.z = (uint16_t)f2bf(acc.z); o.w = (uint16_t)f2bf(acc.w);
    ((ushort4*)az)[wave * 64 + lane] = o;
}

// ---------------- SpMM (bf16 source): az_bf16 = A * z ----------------
__global__ void k_spmm_bf16(const uint16_t* __restrict__ z, const int* __restrict__ row_ptr,
                            const int* __restrict__ cols_s, const float* __restrict__ vals_s,
                            uint16_t* __restrict__ az, int N) {
    int wave = (int)((blockIdx.x * (size_t)blockDim.x + threadIdx.x) >> 6);
    int lane = threadIdx.x & 63;
    if (wave >= N) return;
    int s = row_ptr[wave], e = row_ptr[wave + 1];
    float4 acc = make_float4(0.f, 0.f, 0.f, 0.f);
    for (int i = s; i < e; i++) {
        int c = cols_s[i];
        float v = vals_s[i];
        ushort4 zr = ((const ushort4*)z)[c * 64 + lane];
        acc.x += v * bf2f(zr.x); acc.y += v * bf2f(zr.y);
        acc.z += v * bf2f(zr.z); acc.w += v * bf2f(zr.w);
    }
    ushort4 o;
    o.x = (uint16_t)f2bf(acc.x); o.y = (uint16_t)f2bf(acc.y);
    o.z = (uint16_t)f2bf(acc.z); o.w = (uint16_t)f2bf(acc.w);
    ((ushort4*)az)[wave * 64 + lane] = o;
}

// ---------------- fused eval: alpha update + z@M (MFMA) + combine + RK4 ----------------
// Eval point z comes from zn (fp32, src_bf16=0) or zeb (bf16, src_bf16=1).
// mode 0: zeb = bf16(z + c1*f) ; S = z + c2*f        (eval1; z == zn)
// mode 1: zeb = bf16(zn + c1*f) ; S += c2*f          (eval2,3)
// mode 2: zn = S + c2*f                              (eval4)
__global__ __launch_bounds__(256, 2) void k_eval(
    const float* __restrict__ zn, const uint16_t* zeb_in, uint16_t* zeb_out,
    float* __restrict__ S, float* __restrict__ zn_out,
    const uint16_t* __restrict__ az, const uint16_t* __restrict__ Mbf,
    const float* __restrict__ x, const float* __restrict__ W_ih,
    const float* __restrict__ W_hh, const float* __restrict__ b_ih,
    const float* __restrict__ b_hh, const float* __restrict__ h,
    float* __restrict__ alpha, int N, int mode, int src_bf16, float c1, float c2)
{
    __shared__ float zs[32][260];          // 33.3 KB
    __shared__ uint16_t bts[2][16][264];   // 16.9 KB
    __shared__ float wihs[2][DD];          //  2.0 KB
    __shared__ float alph_s[32];
    // ~52.4 KB total

    int t = threadIdx.x;
    int r0 = blockIdx.x * 32;

    // phase 0: stage own 32 eval-point rows to LDS (fp32)
    if (src_bf16) {
        #pragma unroll
        for (int i = 0; i < 8; i++) {
            int idx = t + i * 256;          // 0..2047 ushort4 chunks (64/row)
            int row = idx >> 6, c4 = idx & 63;
            int grow = r0 + row;
            ushort4 v = make_ushort4(0, 0, 0, 0);
            if (grow < N) v = ((const ushort4*)zeb_in)[grow * 64 + c4];
            float* dst = &zs[row][c4 * 4];
            dst[0] = bf2f(v.x); dst[1] = bf2f(v.y); dst[2] = bf2f(v.z); dst[3] = bf2f(v.w);
        }
    } else {
        #pragma unroll
        for (int i = 0; i < 8; i++) {
            int idx = t + i * 256;          // 0..2047 float4 chunks (64/row)
            int row = idx >> 6, c4 = idx & 63;
            int grow = r0 + row;
            float4 v = make_float4(0.f, 0.f, 0.f, 0.f);
            if (grow < N) v = ((const float4*)zn)[grow * 64 + c4];
            *(float4*)&zs[row][c4 * 4] = v;
        }
    }
    wihs[0][t] = W_ih[t];
    wihs[1][t] = W_ih[DD + t];
    __syncthreads();

    // phase 1: RNNCell dots -> alpha update -> 0.5*sigmoid(alpha)
    {
        int row = t >> 3, part = t & 7;
        int cbeg = part * 32;
        float s0 = 0.f, s1 = 0.f;
        #pragma unroll 8
        for (int c = cbeg; c < cbeg + 32; c++) {
            float zv = zs[row][c];
            s0 += zv * wihs[0][c];
            s1 += zv * wihs[1][c];
        }
        s0 += __shfl_down(s0, 4, 8); s0 += __shfl_down(s0, 2, 8); s0 += __shfl_down(s0, 1, 8);
        s1 += __shfl_down(s1, 4, 8); s1 += __shfl_down(s1, 2, 8); s1 += __shfl_down(s1, 1, 8);
        if (part == 0) {
            int grow = r0 + row;
            if (grow < N) {
                float h0 = h[grow * 2], h1 = h[grow * 2 + 1];
                float cc0 = b_ih[0] + b_hh[0] + h0 * W_hh[0] + h1 * W_hh[1];
                float cc1 = b_ih[1] + b_hh[1] + h0 * W_hh[2] + h1 * W_hh[3];
                float a0 = tanhf(s0 + cc0);
                float a1 = tanhf(s1 + cc1);
                float al = alpha[grow];
                float anew = al * a0 + a1;
                alpha[grow] = anew;
                alph_s[row] = 0.5f / (1.f + expf(-anew));
            } else {
                alph_s[row] = 0.f;
            }
        }
    }
    __syncthreads();

    // phase 2: A fragments (bf16), full K=256, in registers
    int wv = t >> 6;
    int lane = t & 63;
    int m = lane & 15, quad = lane >> 4;
    int arow = (wv & 1) * 16 + m;
    int whichW = wv >> 1;
    short8 afr[8];
    #pragma unroll
    for (int kt = 0; kt < 8; kt++) {
        int k0 = kt * 32 + quad * 8;
        float4 f0 = *(const float4*)&zs[arow][k0];
        float4 f1 = *(const float4*)&zs[arow][k0 + 4];
        short8 a;
        a[0] = f2bf(f0.x); a[1] = f2bf(f0.y); a[2] = f2bf(f0.z); a[3] = f2bf(f0.w);
        a[4] = f2bf(f1.x); a[5] = f2bf(f1.y); a[6] = f2bf(f1.z); a[7] = f2bf(f1.w);
        afr[kt] = a;
    }

    // phase 3: 8 iterations x 2 column tiles; MFMA + combine + RK4 writes
    for (int nt = 0; nt < 8; nt++) {
        __syncthreads();
        {
            int which = t >> 7;
            int rowb = (t >> 3) & 15;
            int chunk = t & 7;
            int tile = which * 8 + nt;
            const uint16_t* src = Mbf + (tile * 16 + rowb) * DD + chunk * 32;
            short8 v0 = *(const short8*)(src);
            short8 v1 = *(const short8*)(src + 8);
            short8 v2 = *(const short8*)(src + 16);
            short8 v3 = *(const short8*)(src + 24);
            uint16_t* dst = &bts[which][rowb][chunk * 32];
            *(short8*)(dst) = v0;
            *(short8*)(dst + 8) = v1;
            *(short8*)(dst + 16) = v2;
            *(short8*)(dst + 24) = v3;
        }
        __syncthreads();

        f32x4 acc = {0.f, 0.f, 0.f, 0.f};
        #pragma unroll
        for (int kt = 0; kt < 8; kt++) {
            int k0 = kt * 32 + quad * 8;
            short8 b = *(const short8*)&bts[whichW][m][k0];   // M symmetric -> B ok
            acc = __builtin_amdgcn_mfma_f32_16x16x32_bf16(afr[kt], b, acc, 0, 0, 0);
        }

        int lr_base = (wv & 1) * 16 + quad * 4;
        int gcol = (whichW * 8 + nt) * 16 + m;
        #pragma unroll
        for (int r = 0; r < 4; r++) {
            int lr = lr_base + r;
            int grow = r0 + lr;
            if (grow < N) {
                float g = acc[r];
                float zv = zs[lr][gcol];
                float azv = bf2f(az[grow * DD + gcol]);
                float x0v = (gcol < DINF) ? x[grow * DINF + gcol] : 0.f;
                float f = alph_s[lr] * (azv - zv) + g + x0v;
                int idx = grow * DD + gcol;
                if (mode == 0) {
                    zeb_out[idx] = (uint16_t)f2bf(zv + c1 * f);
                    S[idx] = zv + c2 * f;
                } else if (mode == 1) {
                    float zb = zn[idx];
                    zeb_out[idx] = (uint16_t)f2bf(zb + c1 * f);
                    S[idx] += c2 * f;
                } else {
                    zn_out[idx] = S[idx] + c2 * f;
                }
            }
        }
    }
}

// ---------------- output: first 128 cols of zn ----------------
__global__ void k_out(const float* __restrict__ zn, float* __restrict__ out, int N) {
    int idx = blockIdx.x * blockDim.x + threadIdx.x;
    if (idx < N * 32) {
        int row = idx >> 5, c4 = idx & 31;
        ((float4*)out)[idx] = ((const float4*)zn)[row * 64 + c4];
    }
}

// ---------------- diagnostic: ws too small -> distinctive output ----------------
__global__ void k_fill(float* __restrict__ out, int n, float v) {
    int idx = blockIdx.x * blockDim.x + threadIdx.x;
    if (idx < n) out[idx] = v;
}

static inline size_t alignup(size_t v) { return (v + 255) & ~(size_t)255; }

extern "C" void kernel_launch(void* const* d_in, const int* in_sizes, int n_in,
                              void* d_out, int out_size, void* d_ws, size_t ws_size,
                              hipStream_t stream) {
    const float* x      = (const float*)d_in[0];
    const int*   erow   = (const int*)d_in[1];
    const int*   ecol   = (const int*)d_in[2];
    const float* evals  = (const float*)d_in[3];
    const float* W_ih   = (const float*)d_in[4];
    const float* W_hh   = (const float*)d_in[5];
    const float* b_ih   = (const float*)d_in[6];
    const float* b_hh   = (const float*)d_in[7];
    const float* h      = (const float*)d_in[8];
    const float* alpha0 = (const float*)d_in[9];
    const float* W      = (const float*)d_in[10];
    const float* dvec   = (const float*)d_in[11];

    int N = in_sizes[0] / DINF;
    int E = in_sizes[1];

    char* w = (char*)d_ws;
    float* zn = (float*)w;        w += alignup((size_t)N * DD * 4);   // 102.4 MB
    float* S  = (float*)w;        w += alignup((size_t)N * DD * 4);   // 102.4 MB
    uint16_t* zeb = (uint16_t*)w; w += alignup((size_t)N * DD * 2);   //  51.2 MB
    float* alpha = (float*)w;     w += alignup((size_t)N * 4);
    uint16_t* Mbf = (uint16_t*)w; w += alignup((size_t)DD * DD * 2);
    int* counts = (int*)w;        w += alignup((size_t)(N + 1) * 4);
    int* row_ptr = (int*)w;       w += alignup((size_t)(N + 1) * 4);
    int* cursor = (int*)w;        w += alignup((size_t)(N + 1) * 4);
    int* cols_s = (int*)w;        w += alignup((size_t)E * 4);
    float* vals_s = (float*)w;    w += alignup((size_t)E * 4);
    size_t need = (size_t)(w - (char*)d_ws);    // ~264 MB

    // az (bf16, N*DD*2 = 51.2 MB) lives in d_out (N*DINF*4 = 51.2 MB) as scratch;
    // k_out overwrites it at the very end.
    uint16_t* az = (uint16_t*)d_out;

    if (ws_size < need) {
        // distinctive signature so the failure mode is identifiable from absmax
        k_fill<<<(out_size + 255) / 256, 256, 0, stream>>>((float*)d_out, out_size, 1000.0f);
        return;
    }

    // CSR build (once per launch, reused by all 8 evals)
    hipMemsetAsync(counts, 0, (size_t)(N + 1) * 4, stream);
    k_hist<<<(E + 255) / 256, 256, 0, stream>>>(erow, counts, E);
    k_scan<<<1, 1024, 0, stream>>>(counts, row_ptr, cursor, N + 1);
    k_scatter<<<(E + 255) / 256, 256, 0, stream>>>(erow, ecol, evals, cursor, cols_s, vals_s, E);

    // M = (W*clip(d))@W^T - I (symmetric), bf16
    k_build_m<<<DD, DD, 0, stream>>>(W, dvec, Mbf);

    // state init
    k_init<<<(N * 64 + 255) / 256, 256, 0, stream>>>(x, alpha0, zn, alpha, N);

    const float dt = 0.45f;  // T_END / N_STEPS
    int gs = (N + 3) / 4, ge = (N + 31) / 32;
    for (int s = 0; s < 2; s++) {
        // eval1: k1 at zn (fp32 source)
        k_spmm_f32<<<gs, 256, 0, stream>>>(zn, row_ptr, cols_s, vals_s, az, N);
        k_eval<<<ge, 256, 0, stream>>>(zn, nullptr, zeb, S, nullptr, az, Mbf, x,
                                       W_ih, W_hh, b_ih, b_hh, h, alpha,
                                       N, 0, 0, 0.5f * dt, dt / 6.f);
        // eval2: k2 at zeb
        k_spmm_bf16<<<gs, 256, 0, stream>>>(zeb, row_ptr, cols_s, vals_s, az, N);
        k_eval<<<ge, 256, 0, stream>>>(zn, zeb, zeb, S, nullptr, az, Mbf, x,
                                       W_ih, W_hh, b_ih, b_hh, h, alpha,
                                       N, 1, 1, 0.5f * dt, dt / 3.f);
        // eval3: k3 at zeb
        k_spmm_bf16<<<gs, 256, 0, stream>>>(zeb, row_ptr, cols_s, vals_s, az, N);
        k_eval<<<ge, 256, 0, stream>>>(zn, zeb, zeb, S, nullptr, az, Mbf, x,
                                       W_ih, W_hh, b_ih, b_hh, h, alpha,
                                       N, 1, 1, dt, dt / 3.f);
        // eval4: k4 at zeb -> new zn
        k_spmm_bf16<<<gs, 256, 0, stream>>>(zeb, row_ptr, cols_s, vals_s, az, N);
        k_eval<<<ge, 256, 0, stream>>>(zn, zeb, zeb, S, zn, az, Mbf, x,
                                       W_ih, W_hh, b_ih, b_hh, h, alpha,
                                       N, 2, 1, 0.f, dt / 6.f);
    }

    k_out<<<(N * 32 + 255) / 256, 256, 0, stream>>>(zn, (float*)d_out, N);
}

// Round 4
// 2017.047 us; speedup vs baseline: 1.5281x; 1.5281x over previous
//
#include <hip/hip_runtime.h>
#include <stdint.h>

#define DD 256
#define DINF 128

typedef __attribute__((ext_vector_type(8))) short short8;
typedef __attribute__((ext_vector_type(4))) float f32x4;

__device__ __forceinline__ short f2bf(float f) {
    union { float f; uint32_t u; } c{f};
    uint32_t r = (c.u + 0x7fffu + ((c.u >> 16) & 1u)) >> 16;
    return (short)(uint16_t)r;
}

__device__ __forceinline__ float bf2f(uint16_t b) {
    union { uint32_t u; float f; } c;
    c.u = ((uint32_t)b) << 16;
    return c.f;
}

// ---------------- CSR build ----------------
__global__ void k_hist(const int* __restrict__ rows, int* __restrict__ counts, int E) {
    int e = blockIdx.x * blockDim.x + threadIdx.x;
    if (e < E) atomicAdd(&counts[rows[e] + 1], 1);
}

// 3-kernel parallel scan (counts -> inclusive prefix = row_ptr)
__global__ void k_scan1(const int* __restrict__ counts, int* __restrict__ part,
                        int* __restrict__ blksum, int n1) {
    __shared__ int tmp[1024];
    int b = blockIdx.x, t = threadIdx.x, i = b * 1024 + t;
    int v = (i < n1) ? counts[i] : 0;
    tmp[t] = v;
    __syncthreads();
    for (int off = 1; off < 1024; off <<= 1) {
        int a = (t >= off) ? tmp[t - off] : 0;
        __syncthreads();
        tmp[t] += a;
        __syncthreads();
    }
    if (i < n1) part[i] = tmp[t];
    if (t == 1023) blksum[b] = tmp[t];
}

__global__ void k_scan2(int* __restrict__ blksum, int nb) {
    __shared__ int tmp[1024];
    int t = threadIdx.x;
    int v = (t < nb) ? blksum[t] : 0;
    tmp[t] = v;
    __syncthreads();
    for (int off = 1; off < 1024; off <<= 1) {
        int a = (t >= off) ? tmp[t - off] : 0;
        __syncthreads();
        tmp[t] += a;
        __syncthreads();
    }
    if (t < nb) blksum[t] = tmp[t];
}

__global__ void k_scan3(const int* __restrict__ blksum, int* __restrict__ row_ptr,
                        int* __restrict__ cursor, int n1) {
    int i = blockIdx.x * blockDim.x + threadIdx.x;
    if (i < n1) {
        int b = i >> 10;
        int off = (b > 0) ? blksum[b - 1] : 0;
        int v = cursor[i] + off;   // cursor holds block-local inclusive scan
        row_ptr[i] = v;
        cursor[i] = v;
    }
}

__global__ void k_scatter(const int* __restrict__ rows, const int* __restrict__ cols,
                          const float* __restrict__ vals, int* __restrict__ cursor,
                          int* __restrict__ cols_s, float* __restrict__ vals_s, int E) {
    int e = blockIdx.x * blockDim.x + threadIdx.x;
    if (e < E) {
        int r = rows[e];
        int pos = atomicAdd(&cursor[r], 1);
        cols_s[pos] = cols[e];
        vals_s[pos] = vals[e];
    }
}

// ---------------- M = (W*clip(d))@W^T - I, packed in MFMA B-fragment order ----------------
// pk index for element M[n][k]: tile=n>>4, m=n&15, kt=k>>5, quad=(k>>3)&3, j=k&7,
// lane=quad*16+m -> Mpk[((tile*8+kt)*64+lane)*8 + j]
__global__ void k_build_m(const float* __restrict__ W, const float* __restrict__ dvec,
                          uint16_t* __restrict__ Mpk) {
    __shared__ float u[DD];
    int n = blockIdx.x, k = threadIdx.x;
    float dj = dvec[k];
    dj = fminf(fmaxf(dj, 0.f), 1.f);
    u[k] = W[n * DD + k] * dj;
    __syncthreads();
    float acc = 0.f;
    for (int j = 0; j < DD; j++) acc += u[j] * W[k * DD + j];
    acc -= (n == k) ? 1.f : 0.f;
    int tile = n >> 4, m = n & 15, kt = k >> 5, quad = (k >> 3) & 3, j = k & 7;
    int lane = quad * 16 + m;
    Mpk[(((tile * 8 + kt) * 64 + lane) << 3) + j] = (uint16_t)f2bf(acc);
}

// ---------------- init: zn = [x,0] fp32, zeb = bf16(zn), alpha = alpha0 ----------------
__global__ void k_init(const float* __restrict__ x, const float* __restrict__ alpha0,
                       float* __restrict__ zn, uint16_t* __restrict__ zeb,
                       float* __restrict__ alpha, int N) {
    int idx = blockIdx.x * blockDim.x + threadIdx.x;
    int total = N * 64;
    if (idx < total) {
        int row = idx >> 6, c4 = idx & 63;
        float4 v;
        if (c4 < 32) v = ((const float4*)x)[(size_t)row * 32 + c4];
        else v = make_float4(0.f, 0.f, 0.f, 0.f);
        ((float4*)zn)[idx] = v;
        ushort4 b;
        b.x = (uint16_t)f2bf(v.x); b.y = (uint16_t)f2bf(v.y);
        b.z = (uint16_t)f2bf(v.z); b.w = (uint16_t)f2bf(v.w);
        ((ushort4*)zeb)[idx] = b;
    }
    if (idx < N) alpha[idx] = alpha0[idx];
}

// ---------------- SpMM: az = bf16(A * zeb) (CSR, one wave per row) ----------------
__global__ void k_spmm(const uint16_t* __restrict__ z, const int* __restrict__ row_ptr,
                       const int* __restrict__ cols_s, const float* __restrict__ vals_s,
                       uint16_t* __restrict__ az, int N) {
    int wave = (int)((blockIdx.x * (size_t)blockDim.x + threadIdx.x) >> 6);
    int lane = threadIdx.x & 63;
    if (wave >= N) return;
    int s = row_ptr[wave], e = row_ptr[wave + 1];
    float4 acc = make_float4(0.f, 0.f, 0.f, 0.f);
    int c_next = 0; float v_next = 0.f;
    if (s < e) { c_next = cols_s[s]; v_next = vals_s[s]; }
    for (int i = s; i < e; i++) {
        int c = c_next; float v = v_next;
        if (i + 1 < e) { c_next = cols_s[i + 1]; v_next = vals_s[i + 1]; }
        ushort4 zr = ((const ushort4*)z)[(size_t)c * 64 + lane];
        acc.x += v * bf2f(zr.x); acc.y += v * bf2f(zr.y);
        acc.z += v * bf2f(zr.z); acc.w += v * bf2f(zr.w);
    }
    ushort4 o;
    o.x = (uint16_t)f2bf(acc.x); o.y = (uint16_t)f2bf(acc.y);
    o.z = (uint16_t)f2bf(acc.z); o.w = (uint16_t)f2bf(acc.w);
    ((ushort4*)az)[(size_t)wave * 64 + lane] = o;
}

// ---------------- fused eval ----------------
// Eval point = zeb (bf16). f = alph*(az - z) + z@M + x0
// mode 0: zeb = bf16(zn + c1*f) ; S = zn + c2*f       (eval1)
// mode 1: zeb = bf16(zn + c1*f) ; S += c2*f           (eval2,3)
// mode 2: zn = S + c2*f ; zeb = bf16(zn)              (eval4)
__global__ __launch_bounds__(256, 4) void k_eval(
    const float* __restrict__ zn, const uint16_t* zeb_in, uint16_t* zeb_out,
    float* __restrict__ S, float* __restrict__ zn_out,
    const uint16_t* __restrict__ az, const uint16_t* __restrict__ Mpk,
    const float* __restrict__ x, const float* __restrict__ W_ih,
    const float* __restrict__ W_hh, const float* __restrict__ b_ih,
    const float* __restrict__ b_hh, const float* __restrict__ h,
    float* __restrict__ alpha, int N, int mode, float c1, float c2)
{
    __shared__ uint16_t zs[32][264];   // eval-point rows, bf16   16.9 KB
    __shared__ uint16_t gs[32][260];   // z@M result, bf16        16.6 KB
    __shared__ float wihs[2][DD];      //                          2.0 KB
    __shared__ float alph_s[32];
    // ~35.7 KB -> 4 blocks/CU

    int t = threadIdx.x;
    int r0 = blockIdx.x * 32;

    // phase 0: stage own 32 bf16 rows
    #pragma unroll
    for (int i = 0; i < 8; i++) {
        int idx = t + i * 256;
        int row = idx >> 6, c4 = idx & 63;
        int grow = r0 + row;
        ushort4 v = make_ushort4(0, 0, 0, 0);
        if (grow < N) v = ((const ushort4*)zeb_in)[(size_t)grow * 64 + c4];
        *(ushort4*)&zs[row][c4 * 4] = v;
    }
    wihs[0][t] = W_ih[t];
    wihs[1][t] = W_ih[DD + t];
    __syncthreads();

    // phase 1: RNNCell dots -> alpha update -> 0.5*sigmoid(alpha)
    {
        int row = t >> 3, part = t & 7;
        int cbeg = part * 32;
        float s0 = 0.f, s1 = 0.f;
        #pragma unroll 8
        for (int c = cbeg; c < cbeg + 32; c++) {
            float zv = bf2f(zs[row][c]);
            s0 += zv * wihs[0][c];
            s1 += zv * wihs[1][c];
        }
        s0 += __shfl_down(s0, 4, 8); s0 += __shfl_down(s0, 2, 8); s0 += __shfl_down(s0, 1, 8);
        s1 += __shfl_down(s1, 4, 8); s1 += __shfl_down(s1, 2, 8); s1 += __shfl_down(s1, 1, 8);
        if (part == 0) {
            int grow = r0 + row;
            if (grow < N) {
                float h0 = h[grow * 2], h1 = h[grow * 2 + 1];
                float cc0 = b_ih[0] + b_hh[0] + h0 * W_hh[0] + h1 * W_hh[1];
                float cc1 = b_ih[1] + b_hh[1] + h0 * W_hh[2] + h1 * W_hh[3];
                float a0 = tanhf(s0 + cc0);
                float a1 = tanhf(s1 + cc1);
                float al = alpha[grow];
                float anew = al * a0 + a1;
                alpha[grow] = anew;
                alph_s[row] = 0.5f / (1.f + expf(-anew));
            } else {
                alph_s[row] = 0.f;
            }
        }
    }

    // phase 2: A fragments direct from LDS (already bf16)
    int wv = t >> 6;
    int lane = t & 63;
    int m = lane & 15, quad = lane >> 4;
    int arow = (wv & 1) * 16 + m;
    int whichW = wv >> 1;
    short8 afr[8];
    #pragma unroll
    for (int kt = 0; kt < 8; kt++)
        afr[kt] = *(const short8*)&zs[arow][kt * 32 + quad * 8];

    // phase 3: MFMA over 8 column tiles; B fragments direct from global (L2)
    int lrb = (wv & 1) * 16 + quad * 4;
    #pragma unroll
    for (int nt = 0; nt < 8; nt++) {
        int tile = whichW * 8 + nt;
        f32x4 acc = {0.f, 0.f, 0.f, 0.f};
        #pragma unroll
        for (int kt = 0; kt < 8; kt++) {
            short8 b = ((const short8*)Mpk)[(tile * 8 + kt) * 64 + lane];
            acc = __builtin_amdgcn_mfma_f32_16x16x32_bf16(afr[kt], b, acc, 0, 0, 0);
        }
        int gcol = tile * 16 + m;
        #pragma unroll
        for (int r = 0; r < 4; r++)
            gs[lrb + r][gcol] = (uint16_t)f2bf(acc[r]);
    }
    __syncthreads();

    // phase 4: coalesced combine + RK4 (float4 / ushort4 per thread)
    #pragma unroll
    for (int i = 0; i < 8; i++) {
        int idx = t + i * 256;
        int row = idx >> 6, c4 = idx & 63;
        int grow = r0 + row;
        if (grow >= N) continue;
        size_t b4 = (size_t)grow * 64 + c4;       // float4/ushort4 index
        float al = alph_s[row];
        ushort4 a4 = ((const ushort4*)az)[b4];
        ushort4 z4 = *(const ushort4*)&zs[row][c4 * 4];
        ushort4 g4 = *(const ushort4*)&gs[row][c4 * 4];
        float4 x4 = make_float4(0.f, 0.f, 0.f, 0.f);
        if (c4 < 32) x4 = ((const float4*)x)[(size_t)grow * 32 + c4];
        float f0 = al * (bf2f(a4.x) - bf2f(z4.x)) + bf2f(g4.x) + x4.x;
        float f1 = al * (bf2f(a4.y) - bf2f(z4.y)) + bf2f(g4.y) + x4.y;
        float f2 = al * (bf2f(a4.z) - bf2f(z4.z)) + bf2f(g4.z) + x4.z;
        float f3 = al * (bf2f(a4.w) - bf2f(z4.w)) + bf2f(g4.w) + x4.w;
        if (mode == 0) {
            float4 zb = ((const float4*)zn)[b4];
            ushort4 o;
            o.x = (uint16_t)f2bf(zb.x + c1 * f0); o.y = (uint16_t)f2bf(zb.y + c1 * f1);
            o.z = (uint16_t)f2bf(zb.z + c1 * f2); o.w = (uint16_t)f2bf(zb.w + c1 * f3);
            ((ushort4*)zeb_out)[b4] = o;
            float4 s4;
            s4.x = zb.x + c2 * f0; s4.y = zb.y + c2 * f1;
            s4.z = zb.z + c2 * f2; s4.w = zb.w + c2 * f3;
            ((float4*)S)[b4] = s4;
        } else if (mode == 1) {
            float4 zb = ((const float4*)zn)[b4];
            ushort4 o;
            o.x = (uint16_t)f2bf(zb.x + c1 * f0); o.y = (uint16_t)f2bf(zb.y + c1 * f1);
            o.z = (uint16_t)f2bf(zb.z + c1 * f2); o.w = (uint16_t)f2bf(zb.w + c1 * f3);
            ((ushort4*)zeb_out)[b4] = o;
            float4 s4 = ((const float4*)S)[b4];
            s4.x += c2 * f0; s4.y += c2 * f1; s4.z += c2 * f2; s4.w += c2 * f3;
            ((float4*)S)[b4] = s4;
        } else {
            float4 s4 = ((const float4*)S)[b4];
            float4 zr;
            zr.x = s4.x + c2 * f0; zr.y = s4.y + c2 * f1;
            zr.z = s4.z + c2 * f2; zr.w = s4.w + c2 * f3;
            ((float4*)zn_out)[b4] = zr;
            ushort4 o;
            o.x = (uint16_t)f2bf(zr.x); o.y = (uint16_t)f2bf(zr.y);
            o.z = (uint16_t)f2bf(zr.z); o.w = (uint16_t)f2bf(zr.w);
            ((ushort4*)zeb_out)[b4] = o;
        }
    }
}

// ---------------- output: first 128 cols of zn ----------------
__global__ void k_out(const float* __restrict__ zn, float* __restrict__ out, int N) {
    int idx = blockIdx.x * blockDim.x + threadIdx.x;
    if (idx < N * 32) {
        int row = idx >> 5, c4 = idx & 31;
        ((float4*)out)[idx] = ((const float4*)zn)[(size_t)row * 64 + c4];
    }
}

__global__ void k_fill(float* __restrict__ out, int n, float v) {
    int idx = blockIdx.x * blockDim.x + threadIdx.x;
    if (idx < n) out[idx] = v;
}

static inline size_t alignup(size_t v) { return (v + 255) & ~(size_t)255; }

extern "C" void kernel_launch(void* const* d_in, const int* in_sizes, int n_in,
                              void* d_out, int out_size, void* d_ws, size_t ws_size,
                              hipStream_t stream) {
    const float* x      = (const float*)d_in[0];
    const int*   erow   = (const int*)d_in[1];
    const int*   ecol   = (const int*)d_in[2];
    const float* evals  = (const float*)d_in[3];
    const float* W_ih   = (const float*)d_in[4];
    const float* W_hh   = (const float*)d_in[5];
    const float* b_ih   = (const float*)d_in[6];
    const float* b_hh   = (const float*)d_in[7];
    const float* h      = (const float*)d_in[8];
    const float* alpha0 = (const float*)d_in[9];
    const float* W      = (const float*)d_in[10];
    const float* dvec   = (const float*)d_in[11];

    int N = in_sizes[0] / DINF;
    int E = in_sizes[1];

    char* w = (char*)d_ws;
    float* zn = (float*)w;        w += alignup((size_t)N * DD * 4);   // 102.4 MB
    float* S  = (float*)w;        w += alignup((size_t)N * DD * 4);   // 102.4 MB
    uint16_t* zeb = (uint16_t*)w; w += alignup((size_t)N * DD * 2);   //  51.2 MB
    float* alpha = (float*)w;     w += alignup((size_t)N * 4);
    uint16_t* Mpk = (uint16_t*)w; w += alignup((size_t)DD * DD * 2);
    int* counts = (int*)w;        w += alignup((size_t)(N + 1) * 4);
    int* row_ptr = (int*)w;       w += alignup((size_t)(N + 1) * 4);
    int* cursor = (int*)w;        w += alignup((size_t)(N + 1) * 4);
    int* blksum = (int*)w;        w += alignup((size_t)1024 * 4);
    int* cols_s = (int*)w;        w += alignup((size_t)E * 4);
    float* vals_s = (float*)w;    w += alignup((size_t)E * 4);
    size_t need = (size_t)(w - (char*)d_ws);

    // az (bf16, 51.2 MB) lives in d_out (51.2 MB) as scratch; k_out overwrites last.
    uint16_t* az = (uint16_t*)d_out;

    if (ws_size < need) {
        k_fill<<<(out_size + 255) / 256, 256, 0, stream>>>((float*)d_out, out_size, 1000.0f);
        return;
    }

    int n1 = N + 1, nb = (n1 + 1023) / 1024;
    hipMemsetAsync(counts, 0, (size_t)n1 * 4, stream);
    k_hist<<<(E + 255) / 256, 256, 0, stream>>>(erow, counts, E);
    k_scan1<<<nb, 1024, 0, stream>>>(counts, cursor, blksum, n1);
    k_scan2<<<1, 1024, 0, stream>>>(blksum, nb);
    k_scan3<<<(n1 + 255) / 256, 256, 0, stream>>>(blksum, row_ptr, cursor, n1);
    k_scatter<<<(E + 255) / 256, 256, 0, stream>>>(erow, ecol, evals, cursor, cols_s, vals_s, E);

    k_build_m<<<DD, DD, 0, stream>>>(W, dvec, Mpk);
    k_init<<<(N * 64 + 255) / 256, 256, 0, stream>>>(x, alpha0, zn, zeb, alpha, N);

    const float dt = 0.45f;  // T_END / N_STEPS
    int gs = (N + 3) / 4, ge = (N + 31) / 32;
    for (int s = 0; s < 2; s++) {
        k_spmm<<<gs, 256, 0, stream>>>(zeb, row_ptr, cols_s, vals_s, az, N);
        k_eval<<<ge, 256, 0, stream>>>(zn, zeb, zeb, S, nullptr, az, Mpk, x,
                                       W_ih, W_hh, b_ih, b_hh, h, alpha,
                                       N, 0, 0.5f * dt, dt / 6.f);
        k_spmm<<<gs, 256, 0, stream>>>(zeb, row_ptr, cols_s, vals_s, az, N);
        k_eval<<<ge, 256, 0, stream>>>(zn, zeb, zeb, S, nullptr, az, Mpk, x,
                                       W_ih, W_hh, b_ih, b_hh, h, alpha,
                                       N, 1, 0.5f * dt, dt / 3.f);
        k_spmm<<<gs, 256, 0, stream>>>(zeb, row_ptr, cols_s, vals_s, az, N);
        k_eval<<<ge, 256, 0, stream>>>(zn, zeb, zeb, S, nullptr, az, Mpk, x,
                                       W_ih, W_hh, b_ih, b_hh, h, alpha,
                                       N, 1, dt, dt / 3.f);
        k_spmm<<<gs, 256, 0, stream>>>(zeb, row_ptr, cols_s, vals_s, az, N);
        k_eval<<<ge, 256, 0, stream>>>(zn, zeb, zeb, S, zn, az, Mpk, x,
                                       W_ih, W_hh, b_ih, b_hh, h, alpha,
                                       N, 2, 0.f, dt / 6.f);
    }

    k_out<<<(N * 32 + 255) / 256, 256, 0, stream>>>(zn, (float*)d_out, N);
}